// Round 1
// baseline (384.215 us; speedup 1.0000x reference)
//
#include <hip/hip_runtime.h>

#define DIM    768
#define HEADS  12
#define HD     64
#define BB     4
#define PP     2048
#define MTOT   8192   /* BB*PP */
#define NQKV   2304

typedef unsigned short bf16s;                                   // bf16 storage
typedef short bf16x8 __attribute__((ext_vector_type(8)));       // MFMA A/B frag
typedef float f32x4  __attribute__((ext_vector_type(4)));       // MFMA C/D frag

__device__ __forceinline__ bf16s f2bf(float f) {
    unsigned int u = __float_as_uint(f);
    unsigned int r = u + 0x7fffu + ((u >> 16) & 1u);            // RNE
    return (bf16s)(r >> 16);
}
__device__ __forceinline__ float bf2f(bf16s s) {
    return __uint_as_float(((unsigned int)s) << 16);
}

// ---------------------------------------------------------------- LayerNorm
__global__ __launch_bounds__(256) void ln_kernel(
        const float* __restrict__ x, const float* __restrict__ w,
        const float* __restrict__ b, bf16s* __restrict__ xn) {
    int row = blockIdx.x;
    const float* xr = x + (size_t)row * DIM;
    int t = threadIdx.x;
    float v0 = xr[t], v1 = xr[t + 256], v2 = xr[t + 512];
    float s  = v0 + v1 + v2;
    float ss = v0*v0 + v1*v1 + v2*v2;
    for (int off = 32; off; off >>= 1) {
        s  += __shfl_down(s, off);
        ss += __shfl_down(ss, off);
    }
    __shared__ float red[8];
    int wid = t >> 6, lane = t & 63;
    if (lane == 0) { red[wid] = s; red[4 + wid] = ss; }
    __syncthreads();
    if (t == 0) {
        float S  = red[0] + red[1] + red[2] + red[3];
        float SS = red[4] + red[5] + red[6] + red[7];
        float mean = S * (1.0f / DIM);
        float var  = SS * (1.0f / DIM) - mean * mean;
        red[0] = mean;
        red[1] = rsqrtf(var + 1e-5f);
    }
    __syncthreads();
    float mean = red[0], inv = red[1];
    bf16s* xo = xn + (size_t)row * DIM;
    xo[t]       = f2bf((v0 - mean) * inv * w[t]       + b[t]);
    xo[t + 256] = f2bf((v1 - mean) * inv * w[t + 256] + b[t + 256]);
    xo[t + 512] = f2bf((v2 - mean) * inv * w[t + 512] + b[t + 512]);
}

// ------------------------------------------------- transpose + cast weights
// dst[n][k] = src[k][n]; optional lo-residual output
template<bool LO>
__global__ __launch_bounds__(256) void transpose_cast(
        const float* __restrict__ src, bf16s* __restrict__ dst,
        bf16s* __restrict__ dst_lo, int Kdim, int Ndim) {
    __shared__ float tile[32][33];
    int n0 = blockIdx.x * 32, k0 = blockIdx.y * 32;
    int tx = threadIdx.x, ty = threadIdx.y;
    #pragma unroll
    for (int i = 0; i < 4; ++i)
        tile[ty + 8*i][tx] = src[(size_t)(k0 + ty + 8*i) * Ndim + n0 + tx];
    __syncthreads();
    #pragma unroll
    for (int i = 0; i < 4; ++i) {
        float v = tile[tx][ty + 8*i];
        size_t oidx = (size_t)(n0 + ty + 8*i) * Kdim + k0 + tx;
        bf16s hi = f2bf(v);
        dst[oidx] = hi;
        if (LO) dst_lo[oidx] = f2bf(v - bf2f(hi));
    }
}

// ----------------------------------------------------------------- GEMM
// C[M x N] = A[M x 768(K)] @ Bt[N x 768]^T ; 128x128 tile, 4 waves (2x2 of 64x64)
// MODE 0: N=2304, scatter to Q/K/V [B,H,P,D] bf16, +bv on V
// MODE 1: N=768, K'=3*768 (Ah*Bh + Ah*Bl + Al*Bh), out fp32 + bfc
template<int MODE>
__global__ __launch_bounds__(256) void gemm_bt(
        const bf16s* __restrict__ A0, const bf16s* __restrict__ A1,
        const bf16s* __restrict__ B0, const bf16s* __restrict__ B1,
        const float* __restrict__ bias,
        bf16s* __restrict__ Qo, bf16s* __restrict__ Ko, bf16s* __restrict__ Vo,
        float* __restrict__ out) {
    const int NT = (MODE == 0 ? NQKV / 128 : DIM / 128);
    int bid = blockIdx.x;
    int nt = bid % NT, mt = bid / NT;
    int m0 = mt * 128, n0 = nt * 128;
    __shared__ bf16s As[128][72];
    __shared__ bf16s Bs[128][72];
    int t = threadIdx.x;
    int lane = t & 63, w = t >> 6;
    int wr = w >> 1, wc = w & 1;
    int lr = lane & 15, lg = lane >> 4;
    f32x4 acc[4][4] = {};
    const int KI = (MODE == 0 ? DIM / 64 : 3 * DIM / 64);
    for (int it = 0; it < KI; ++it) {
        int seg = it / (DIM / 64);
        int k0  = (it % (DIM / 64)) * 64;
        const bf16s* Ap = A0;
        const bf16s* Bp = B0;
        if (MODE == 1) {
            Ap = (seg == 2) ? A1 : A0;
            Bp = (seg == 1) ? B1 : B0;
        }
        #pragma unroll
        for (int i = 0; i < 4; ++i) {
            int flat = i * 2048 + t * 8;
            int r = flat >> 6, c = flat & 63;
            *(uint4*)&As[r][c] = *(const uint4*)&Ap[(size_t)(m0 + r) * DIM + k0 + c];
            *(uint4*)&Bs[r][c] = *(const uint4*)&Bp[(size_t)(n0 + r) * DIM + k0 + c];
        }
        __syncthreads();
        #pragma unroll
        for (int kk = 0; kk < 2; ++kk) {
            bf16x8 af[4], bfr[4];
            #pragma unroll
            for (int i = 0; i < 4; ++i) {
                af[i]  = *(const bf16x8*)&As[wr*64 + i*16 + lr][kk*32 + lg*8];
                bfr[i] = *(const bf16x8*)&Bs[wc*64 + i*16 + lr][kk*32 + lg*8];
            }
            #pragma unroll
            for (int mi = 0; mi < 4; ++mi)
                #pragma unroll
                for (int ni = 0; ni < 4; ++ni)
                    acc[mi][ni] = __builtin_amdgcn_mfma_f32_16x16x32_bf16(
                        af[mi], bfr[ni], acc[mi][ni], 0, 0, 0);
        }
        __syncthreads();
    }
    #pragma unroll
    for (int mi = 0; mi < 4; ++mi) {
        #pragma unroll
        for (int ni = 0; ni < 4; ++ni) {
            #pragma unroll
            for (int r = 0; r < 4; ++r) {
                int m = m0 + wr*64 + mi*16 + lg*4 + r;
                int n = n0 + wc*64 + ni*16 + lr;
                float val = acc[mi][ni][r];
                if (MODE == 0) {
                    int which  = n / DIM;
                    int within = n % DIM;
                    int h = within >> 6, d = within & 63;
                    int b = m >> 11, p = m & 2047;
                    size_t idx = (((size_t)(b * HEADS + h)) * PP + p) * HD + d;
                    if (which == 2)      { Vo[idx] = f2bf(val + bias[within]); }
                    else if (which == 1) { Ko[idx] = f2bf(val); }
                    else                 { Qo[idx] = f2bf(val); }
                } else {
                    out[(size_t)m * DIM + n] = val + bias[n];
                }
            }
        }
    }
}

// ------------------------------------------------------------ attention
// one block = one (b,h,qtile-of-64); 4 waves x 16 q-rows; online softmax
__global__ __launch_bounds__(256) void attn_kernel(
        const bf16s* __restrict__ Q, const bf16s* __restrict__ K,
        const bf16s* __restrict__ V,
        bf16s* __restrict__ Oh, bf16s* __restrict__ Ol) {
    int bid = blockIdx.x;
    int qt  = bid & 31;
    int tmp = bid >> 5;
    int h   = tmp % HEADS;
    int b   = tmp / HEADS;
    const size_t headoff = ((size_t)(b * HEADS + h)) * PP * HD;
    const bf16s* Qh = Q + headoff;
    const bf16s* Kh = K + headoff;
    const bf16s* Vh = V + headoff;
    __shared__ bf16s Qs[64][72];
    __shared__ bf16s Ks[64][72];
    __shared__ bf16s Vt[64][72];      // transposed: Vt[d][kv]
    __shared__ bf16s Ps[4][16][72];
    int t = threadIdx.x, lane = t & 63, w = t >> 6;
    int lr = lane & 15, lg = lane >> 4;
    int q0 = qt * 64;
    #pragma unroll
    for (int i = 0; i < 2; ++i) {
        int flat = i * 2048 + t * 8;
        int r = flat >> 6, c = flat & 63;
        *(uint4*)&Qs[r][c] = *(const uint4*)&Qh[(size_t)(q0 + r) * HD + c];
    }
    __syncthreads();
    bf16x8 qf[2];
    qf[0] = *(const bf16x8*)&Qs[w*16 + lr][lg*8];
    qf[1] = *(const bf16x8*)&Qs[w*16 + lr][32 + lg*8];
    float mrow[4], lrow[4];
    f32x4 o[4] = {};
    #pragma unroll
    for (int r = 0; r < 4; ++r) { mrow[r] = -1e30f; lrow[r] = 0.f; }
    const float scale = 0.125f;
    for (int j = 0; j < 32; ++j) {
        __syncthreads();   // prev iter's reads of Ks/Vt complete
        #pragma unroll
        for (int i = 0; i < 2; ++i) {
            int flat = i * 2048 + t * 8;
            int r = flat >> 6, c = flat & 63;
            *(uint4*)&Ks[r][c] = *(const uint4*)&Kh[(size_t)(j*64 + r) * HD + c];
            uint4 vv = *(const uint4*)&Vh[(size_t)(j*64 + r) * HD + c];
            const bf16s* ve = (const bf16s*)&vv;
            #pragma unroll
            for (int e = 0; e < 8; ++e) Vt[c + e][r] = ve[e];
        }
        __syncthreads();
        f32x4 s[4] = {};
        #pragma unroll
        for (int kk = 0; kk < 2; ++kk)
            #pragma unroll
            for (int n = 0; n < 4; ++n) {
                bf16x8 kf = *(const bf16x8*)&Ks[n*16 + lr][kk*32 + lg*8];
                s[n] = __builtin_amdgcn_mfma_f32_16x16x32_bf16(qf[kk], kf, s[n], 0, 0, 0);
            }
        #pragma unroll
        for (int r = 0; r < 4; ++r) {
            int qg = q0 + w*16 + lg*4 + r;
            float mt = -1e30f;
            #pragma unroll
            for (int n = 0; n < 4; ++n) {
                float v = s[n][r] * scale;
                int kg = j*64 + n*16 + lr;
                if (kg == qg) v = -1e30f;
                s[n][r] = v;
                mt = fmaxf(mt, v);
            }
            #pragma unroll
            for (int off = 1; off < 16; off <<= 1) mt = fmaxf(mt, __shfl_xor(mt, off));
            float mn = fmaxf(mrow[r], mt);
            float corr = __expf(mrow[r] - mn);
            mrow[r] = mn;
            float rs = 0.f;
            #pragma unroll
            for (int n = 0; n < 4; ++n) {
                float p = __expf(s[n][r] - mn);
                s[n][r] = p;
                rs += p;
            }
            #pragma unroll
            for (int off = 1; off < 16; off <<= 1) rs += __shfl_xor(rs, off);
            lrow[r] = lrow[r] * corr + rs;
            #pragma unroll
            for (int nd = 0; nd < 4; ++nd) o[nd][r] *= corr;
        }
        #pragma unroll
        for (int r = 0; r < 4; ++r)
            #pragma unroll
            for (int n = 0; n < 4; ++n)
                Ps[w][lg*4 + r][n*16 + lr] = f2bf(s[n][r]);
        __syncthreads();
        #pragma unroll
        for (int kk = 0; kk < 2; ++kk) {
            bf16x8 pf = *(const bf16x8*)&Ps[w][lr][kk*32 + lg*8];
            #pragma unroll
            for (int nd = 0; nd < 4; ++nd) {
                bf16x8 vf = *(const bf16x8*)&Vt[nd*16 + lr][kk*32 + lg*8];
                o[nd] = __builtin_amdgcn_mfma_f32_16x16x32_bf16(pf, vf, o[nd], 0, 0, 0);
            }
        }
    }
    #pragma unroll
    for (int nd = 0; nd < 4; ++nd) {
        #pragma unroll
        for (int r = 0; r < 4; ++r) {
            int q = q0 + w*16 + lg*4 + r;
            int d = nd*16 + lr;
            float v = o[nd][r] / lrow[r];
            size_t m = (size_t)b * PP + q;
            size_t idx = m * DIM + h * HD + d;
            bf16s hi = f2bf(v);
            Oh[idx] = hi;
            Ol[idx] = f2bf(v - bf2f(hi));
        }
    }
}

// ---------------------------------------------------------------- launch
extern "C" void kernel_launch(void* const* d_in, const int* in_sizes, int n_in,
                              void* d_out, int out_size, void* d_ws, size_t ws_size,
                              hipStream_t stream) {
    const float* x    = (const float*)d_in[0];
    const float* ln_w = (const float*)d_in[1];
    const float* ln_b = (const float*)d_in[2];
    const float* Wq   = (const float*)d_in[3];
    const float* Wk   = (const float*)d_in[4];
    const float* Wv   = (const float*)d_in[5];
    const float* bv   = (const float*)d_in[6];
    const float* Wfc  = (const float*)d_in[7];
    const float* bfc  = (const float*)d_in[8];
    float* out = (float*)d_out;

    char* ws = (char*)d_ws;
    size_t off = 0;
    auto alloc = [&](size_t bytes) {
        void* p = ws + off;
        off += (bytes + 255) & ~(size_t)255;
        return p;
    };
    bf16s* xn     = (bf16s*)alloc((size_t)MTOT * DIM * 2);
    bf16s* Wqkv_t = (bf16s*)alloc((size_t)NQKV * DIM * 2);
    bf16s* Wfc_h  = (bf16s*)alloc((size_t)DIM * DIM * 2);
    bf16s* Wfc_l  = (bf16s*)alloc((size_t)DIM * DIM * 2);
    bf16s* Qb     = (bf16s*)alloc((size_t)MTOT * DIM * 2);
    bf16s* Kb     = (bf16s*)alloc((size_t)MTOT * DIM * 2);
    bf16s* Vb     = (bf16s*)alloc((size_t)MTOT * DIM * 2);
    bf16s* Ah     = (bf16s*)alloc((size_t)MTOT * DIM * 2);
    bf16s* Al     = (bf16s*)alloc((size_t)MTOT * DIM * 2);

    ln_kernel<<<MTOT, 256, 0, stream>>>(x, ln_w, ln_b, xn);

    dim3 tb(32, 8);
    transpose_cast<false><<<dim3(24, 24), tb, 0, stream>>>(Wq, Wqkv_t,               nullptr, DIM, DIM);
    transpose_cast<false><<<dim3(24, 24), tb, 0, stream>>>(Wk, Wqkv_t + 768 * 768,   nullptr, DIM, DIM);
    transpose_cast<false><<<dim3(24, 24), tb, 0, stream>>>(Wv, Wqkv_t + 2 * 768 * 768, nullptr, DIM, DIM);
    transpose_cast<true ><<<dim3(24, 24), tb, 0, stream>>>(Wfc, Wfc_h, Wfc_l, DIM, DIM);

    gemm_bt<0><<<(MTOT / 128) * (NQKV / 128), 256, 0, stream>>>(
        xn, nullptr, Wqkv_t, nullptr, bv, Qb, Kb, Vb, nullptr);

    attn_kernel<<<BB * HEADS * 32, 256, 0, stream>>>(Qb, Kb, Vb, Ah, Al);

    gemm_bt<1><<<(MTOT / 128) * (DIM / 128), 256, 0, stream>>>(
        Ah, Al, Wfc_h, Wfc_l, bfc, nullptr, nullptr, nullptr, out);
}

// Round 3
// 244.297 us; speedup vs baseline: 1.5727x; 1.5727x over previous
//
#include <hip/hip_runtime.h>

#define DIM    768
#define HEADS  12
#define HD     64
#define BB     4
#define PP     2048
#define MTOT   8192   /* BB*PP */
#define NQKV   2304

typedef unsigned short bf16s;                                   // bf16 storage
typedef short bf16x8 __attribute__((ext_vector_type(8)));       // MFMA A/B frag
typedef float f32x4  __attribute__((ext_vector_type(4)));       // MFMA C/D frag

__device__ __forceinline__ bf16s f2bf(float f) {
    unsigned int u = __float_as_uint(f);
    unsigned int r = u + 0x7fffu + ((u >> 16) & 1u);            // RNE
    return (bf16s)(r >> 16);
}
__device__ __forceinline__ float bf2f(bf16s s) {
    return __uint_as_float(((unsigned int)s) << 16);
}
__device__ __forceinline__ float exp2g(float x) {
    return __builtin_amdgcn_exp2f(x);                           // v_exp_f32
}

// ---------------------------------------------------------------- LayerNorm
__global__ __launch_bounds__(256) void ln_kernel(
        const float* __restrict__ x, const float* __restrict__ w,
        const float* __restrict__ b, bf16s* __restrict__ xn) {
    int row = blockIdx.x;
    const float* xr = x + (size_t)row * DIM;
    int t = threadIdx.x;
    float v0 = xr[t], v1 = xr[t + 256], v2 = xr[t + 512];
    float s  = v0 + v1 + v2;
    float ss = v0*v0 + v1*v1 + v2*v2;
    for (int off = 32; off; off >>= 1) {
        s  += __shfl_down(s, off);
        ss += __shfl_down(ss, off);
    }
    __shared__ float red[8];
    int wid = t >> 6, lane = t & 63;
    if (lane == 0) { red[wid] = s; red[4 + wid] = ss; }
    __syncthreads();
    if (t == 0) {
        float S  = red[0] + red[1] + red[2] + red[3];
        float SS = red[4] + red[5] + red[6] + red[7];
        float mean = S * (1.0f / DIM);
        float var  = SS * (1.0f / DIM) - mean * mean;
        red[0] = mean;
        red[1] = rsqrtf(var + 1e-5f);
    }
    __syncthreads();
    float mean = red[0], inv = red[1];
    bf16s* xo = xn + (size_t)row * DIM;
    xo[t]       = f2bf((v0 - mean) * inv * w[t]       + b[t]);
    xo[t + 256] = f2bf((v1 - mean) * inv * w[t + 256] + b[t + 256]);
    xo[t + 512] = f2bf((v2 - mean) * inv * w[t + 512] + b[t + 512]);
}

// ------------------------------------------------- transpose + cast weights
template<bool LO>
__global__ __launch_bounds__(256) void transpose_cast(
        const float* __restrict__ src, bf16s* __restrict__ dst,
        bf16s* __restrict__ dst_lo, int Kdim, int Ndim) {
    __shared__ float tile[32][33];
    int n0 = blockIdx.x * 32, k0 = blockIdx.y * 32;
    int tx = threadIdx.x, ty = threadIdx.y;
    #pragma unroll
    for (int i = 0; i < 4; ++i)
        tile[ty + 8*i][tx] = src[(size_t)(k0 + ty + 8*i) * Ndim + n0 + tx];
    __syncthreads();
    #pragma unroll
    for (int i = 0; i < 4; ++i) {
        float v = tile[tx][ty + 8*i];
        size_t oidx = (size_t)(n0 + ty + 8*i) * Kdim + k0 + tx;
        bf16s hi = f2bf(v);
        dst[oidx] = hi;
        if (LO) dst_lo[oidx] = f2bf(v - bf2f(hi));
    }
}

// ----------------------------------------------------------------- GEMM
// C[M x N] = A[M x 768(K)] @ Bt[N x 768]^T ; 128x128 tile, 4 waves (2x2 of 64x64)
// MODE 0: N=2304 -> Q [b,h,p,d], K [b,h,p,d], V^T [b,h,d,p] (+bv)
// MODE 1: N=768, K'=3*768 (Ah*Bh + Ah*Bl + Al*Bh), out fp32 + bfc
template<int MODE>
__global__ __launch_bounds__(256) void gemm_bt(
        const bf16s* __restrict__ A0, const bf16s* __restrict__ A1,
        const bf16s* __restrict__ B0, const bf16s* __restrict__ B1,
        const float* __restrict__ bias,
        bf16s* __restrict__ Qo, bf16s* __restrict__ Ko, bf16s* __restrict__ Vo,
        float* __restrict__ out) {
    const int NT  = (MODE == 0 ? NQKV / 128 : DIM / 128);
    const int NWG = (MTOT / 128) * NT;
    int bid = blockIdx.x;
    bid = (bid & 7) * (NWG / 8) + (bid >> 3);         // XCD swizzle (NWG%8==0)
    int nt = bid % NT, mt = bid / NT;
    int m0 = mt * 128, n0 = nt * 128;
    __shared__ bf16s As[128][72];
    __shared__ bf16s Bs[128][72];
    int t = threadIdx.x;
    int lane = t & 63, w = t >> 6;
    int wr = w >> 1, wc = w & 1;
    int lr = lane & 15, lg = lane >> 4;
    f32x4 acc[4][4] = {};
    const int KI = (MODE == 0 ? DIM / 64 : 3 * DIM / 64);
    for (int it = 0; it < KI; ++it) {
        int seg = it / (DIM / 64);
        int k0  = (it % (DIM / 64)) * 64;
        const bf16s* Ap = A0;
        const bf16s* Bp = B0;
        if (MODE == 1) {
            Ap = (seg == 2) ? A1 : A0;
            Bp = (seg == 1) ? B1 : B0;
        }
        #pragma unroll
        for (int i = 0; i < 4; ++i) {
            int flat = i * 2048 + t * 8;
            int r = flat >> 6, c = flat & 63;
            *(uint4*)&As[r][c] = *(const uint4*)&Ap[(size_t)(m0 + r) * DIM + k0 + c];
            *(uint4*)&Bs[r][c] = *(const uint4*)&Bp[(size_t)(n0 + r) * DIM + k0 + c];
        }
        __syncthreads();
        #pragma unroll
        for (int kk = 0; kk < 2; ++kk) {
            bf16x8 af[4], bfr[4];
            #pragma unroll
            for (int i = 0; i < 4; ++i) {
                af[i]  = *(const bf16x8*)&As[wr*64 + i*16 + lr][kk*32 + lg*8];
                bfr[i] = *(const bf16x8*)&Bs[wc*64 + i*16 + lr][kk*32 + lg*8];
            }
            #pragma unroll
            for (int mi = 0; mi < 4; ++mi)
                #pragma unroll
                for (int ni = 0; ni < 4; ++ni)
                    acc[mi][ni] = __builtin_amdgcn_mfma_f32_16x16x32_bf16(
                        af[mi], bfr[ni], acc[mi][ni], 0, 0, 0);
        }
        __syncthreads();
    }
    if (MODE == 0) {
        #pragma unroll
        for (int mi = 0; mi < 4; ++mi) {
            int m_base = m0 + wr*64 + mi*16 + lg*4;
            int b = m_base >> 11, p = m_base & 2047;
            #pragma unroll
            for (int ni = 0; ni < 4; ++ni) {
                int n = n0 + wc*64 + ni*16 + lr;
                int which = n / DIM, within = n % DIM;
                int hh = within >> 6, d = within & 63;
                if (which == 2) {
                    float bb = bias[within];
                    ushort4 pk;
                    pk.x = f2bf(acc[mi][ni][0] + bb);
                    pk.y = f2bf(acc[mi][ni][1] + bb);
                    pk.z = f2bf(acc[mi][ni][2] + bb);
                    pk.w = f2bf(acc[mi][ni][3] + bb);
                    *(ushort4*)&Vo[(((size_t)(b*HEADS + hh))*HD + d)*PP + p] = pk;
                } else {
                    bf16s* dst = (which == 1) ? Ko : Qo;
                    #pragma unroll
                    for (int r = 0; r < 4; ++r)
                        dst[(((size_t)(b*HEADS + hh))*PP + p + r)*HD + d] =
                            f2bf(acc[mi][ni][r]);
                }
            }
        }
    } else {
        #pragma unroll
        for (int mi = 0; mi < 4; ++mi)
            #pragma unroll
            for (int ni = 0; ni < 4; ++ni)
                #pragma unroll
                for (int r = 0; r < 4; ++r) {
                    int m = m0 + wr*64 + mi*16 + lg*4 + r;
                    int n = n0 + wc*64 + ni*16 + lr;
                    out[(size_t)m * DIM + n] = acc[mi][ni][r] + bias[n];
                }
    }
}

// ------------------------------------------------------------ attention
// one block = one (b,h,qtile-of-64); 4 waves x 16 q-rows
// swapped QK^T: each lane owns ONE q (col) with 16 kv-scores in regs
__global__ __launch_bounds__(256) void attn_kernel(
        const bf16s* __restrict__ Q, const bf16s* __restrict__ K,
        const bf16s* __restrict__ Vt,
        bf16s* __restrict__ Oh, bf16s* __restrict__ Ol) {
    int orig = blockIdx.x;
    int wg = (orig & 7) * 192 + (orig >> 3);   // XCD swizzle: 6 heads per XCD
    int qt  = wg & 31;
    int tmp = wg >> 5;
    int h   = tmp % HEADS;
    int b   = tmp / HEADS;
    const size_t headoff = ((size_t)(b * HEADS + h)) * PP * HD;
    const bf16s* Qh = Q  + headoff;
    const bf16s* Kh = K  + headoff;
    const bf16s* Vh = Vt + headoff;            // [d][p]
    __shared__ bf16s Ks[64][72];
    __shared__ bf16s Vs[64][72];               // rows = d, cols = kv
    __shared__ bf16s Ps[4][16][72];            // per-wave P [q_local][kv_local]
    int t = threadIdx.x, lane = t & 63, w = t >> 6;
    int lr = lane & 15, lg = lane >> 4;
    int q0 = qt * 64;
    int qw0 = q0 + w * 16;
    bf16x8 qf[2];
    qf[0] = *(const bf16x8*)&Qh[(size_t)(qw0 + lr) * HD + lg*8];
    qf[1] = *(const bf16x8*)&Qh[(size_t)(qw0 + lr) * HD + 32 + lg*8];
    float m_run = -1e30f, l_run = 0.f;
    f32x4 o[4] = {};
    const float SC = 0.125f * 1.44269504f;     // scale * log2(e): exp2-domain
    const int qg = q0 + w*16 + lr;             // the q this lane owns
    for (int j = 0; j < 32; ++j) {
        __syncthreads();                       // prev PV reads done
        #pragma unroll
        for (int i = 0; i < 2; ++i) {
            int flat = i * 2048 + t * 8;
            int r = flat >> 6, c = flat & 63;
            *(uint4*)&Ks[r][c] = *(const uint4*)&Kh[(size_t)(j*64 + r) * HD + c];
            *(uint4*)&Vs[r][c] = *(const uint4*)&Vh[(size_t)r * PP + j*64 + c];
        }
        __syncthreads();
        f32x4 s[4] = {};
        #pragma unroll
        for (int kk = 0; kk < 2; ++kk)
            #pragma unroll
            for (int n = 0; n < 4; ++n) {
                bf16x8 kf = *(const bf16x8*)&Ks[n*16 + lr][kk*32 + lg*8];
                s[n] = __builtin_amdgcn_mfma_f32_16x16x32_bf16(kf, qf[kk], s[n], 0, 0, 0);
            }
        // scale + diagonal mask; rows of s = kv, col = this lane's q
        float mt = -1e30f;
        #pragma unroll
        for (int n = 0; n < 4; ++n)
            #pragma unroll
            for (int r = 0; r < 4; ++r) {
                int kg = j*64 + n*16 + lg*4 + r;
                float v = (kg == qg) ? -1e30f : s[n][r] * SC;
                s[n][r] = v;
                mt = fmaxf(mt, v);
            }
        mt = fmaxf(mt, __shfl_xor(mt, 16));
        mt = fmaxf(mt, __shfl_xor(mt, 32));
        float mn = fmaxf(m_run, mt);
        float corr = exp2g(m_run - mn);
        m_run = mn;
        float rs = 0.f;
        #pragma unroll
        for (int n = 0; n < 4; ++n)
            #pragma unroll
            for (int r = 0; r < 4; ++r) {
                float p = exp2g(s[n][r] - mn);
                s[n][r] = p;
                rs += p;
            }
        rs += __shfl_xor(rs, 16);
        rs += __shfl_xor(rs, 32);
        l_run = l_run * corr + rs;
        // pack P -> LDS (row-major per wave, b64 stores)
        #pragma unroll
        for (int n = 0; n < 4; ++n) {
            ushort4 pk;
            pk.x = f2bf(s[n][0]); pk.y = f2bf(s[n][1]);
            pk.z = f2bf(s[n][2]); pk.w = f2bf(s[n][3]);
            *(ushort4*)&Ps[w][lr][n*16 + lg*4] = pk;
        }
        // rescale o with per-row corr (o rows are q = qw0 + lg*4 + r)
        #pragma unroll
        for (int r = 0; r < 4; ++r) {
            float cq = __shfl(corr, lg*4 + r);
            #pragma unroll
            for (int nd = 0; nd < 4; ++nd) o[nd][r] *= cq;
        }
        __syncthreads();                       // P visible (cross-lane)
        #pragma unroll
        for (int kk = 0; kk < 2; ++kk) {
            bf16x8 pf = *(const bf16x8*)&Ps[w][lr][kk*32 + lg*8];
            #pragma unroll
            for (int nd = 0; nd < 4; ++nd) {
                bf16x8 vf = *(const bf16x8*)&Vs[nd*16 + lr][kk*32 + lg*8];
                o[nd] = __builtin_amdgcn_mfma_f32_16x16x32_bf16(pf, vf, o[nd], 0, 0, 0);
            }
        }
    }
    float invl[4];
    #pragma unroll
    for (int r = 0; r < 4; ++r)
        invl[r] = 1.0f / __shfl(l_run, lg*4 + r);
    #pragma unroll
    for (int nd = 0; nd < 4; ++nd) {
        #pragma unroll
        for (int r = 0; r < 4; ++r) {
            int q = qw0 + lg*4 + r;
            int d = nd*16 + lr;
            float v = o[nd][r] * invl[r];
            size_t m = (size_t)b * PP + q;
            size_t idx = m * DIM + h * HD + d;
            bf16s hi = f2bf(v);
            Oh[idx] = hi;
            Ol[idx] = f2bf(v - bf2f(hi));
        }
    }
}

// ---------------------------------------------------------------- launch
extern "C" void kernel_launch(void* const* d_in, const int* in_sizes, int n_in,
                              void* d_out, int out_size, void* d_ws, size_t ws_size,
                              hipStream_t stream) {
    const float* x    = (const float*)d_in[0];
    const float* ln_w = (const float*)d_in[1];
    const float* ln_b = (const float*)d_in[2];
    const float* Wq   = (const float*)d_in[3];
    const float* Wk   = (const float*)d_in[4];
    const float* Wv   = (const float*)d_in[5];
    const float* bv   = (const float*)d_in[6];
    const float* Wfc  = (const float*)d_in[7];
    const float* bfc  = (const float*)d_in[8];
    float* out = (float*)d_out;

    char* ws = (char*)d_ws;
    size_t off = 0;
    auto alloc = [&](size_t bytes) {
        void* p = ws + off;
        off += (bytes + 255) & ~(size_t)255;
        return p;
    };
    bf16s* xn     = (bf16s*)alloc((size_t)MTOT * DIM * 2);
    bf16s* Wqkv_t = (bf16s*)alloc((size_t)NQKV * DIM * 2);
    bf16s* Wfc_h  = (bf16s*)alloc((size_t)DIM * DIM * 2);
    bf16s* Wfc_l  = (bf16s*)alloc((size_t)DIM * DIM * 2);
    bf16s* Qb     = (bf16s*)alloc((size_t)MTOT * DIM * 2);
    bf16s* Kb     = (bf16s*)alloc((size_t)MTOT * DIM * 2);
    bf16s* Vtg    = (bf16s*)alloc((size_t)MTOT * DIM * 2);   // V^T [b,h,d,p]
    bf16s* Ah     = (bf16s*)alloc((size_t)MTOT * DIM * 2);
    bf16s* Al     = (bf16s*)alloc((size_t)MTOT * DIM * 2);

    ln_kernel<<<MTOT, 256, 0, stream>>>(x, ln_w, ln_b, xn);

    dim3 tb(32, 8);
    transpose_cast<false><<<dim3(24, 24), tb, 0, stream>>>(Wq, Wqkv_t,                 nullptr, DIM, DIM);
    transpose_cast<false><<<dim3(24, 24), tb, 0, stream>>>(Wk, Wqkv_t + 768 * 768,     nullptr, DIM, DIM);
    transpose_cast<false><<<dim3(24, 24), tb, 0, stream>>>(Wv, Wqkv_t + 2 * 768 * 768, nullptr, DIM, DIM);
    transpose_cast<true ><<<dim3(24, 24), tb, 0, stream>>>(Wfc, Wfc_h, Wfc_l, DIM, DIM);

    gemm_bt<0><<<(MTOT / 128) * (NQKV / 128), 256, 0, stream>>>(
        xn, nullptr, Wqkv_t, nullptr, bv, Qb, Kb, Vtg, nullptr);

    attn_kernel<<<BB * HEADS * 32, 256, 0, stream>>>(Qb, Kb, Vtg, Ah, Al);

    gemm_bt<1><<<(MTOT / 128) * (DIM / 128), 256, 0, stream>>>(
        Ah, Al, Wfc_h, Wfc_l, bfc, nullptr, nullptr, nullptr, out);
}